// Round 7
// baseline (160.083 us; speedup 1.0000x reference)
//
#include <hip/hip_runtime.h>
#include <math.h>

#define DD 8
#define ZD 16
#define HID 200
#define EPSL 0.1f
#define BS 16          // samples per block
#define NTHREADS 1024  // 16 waves: 4 waves/SIMD (hard VGPR cap 128)
#define NKC 7          // K chunks of 32 (200 -> 224)
#define NMT 13         // unit tiles of 16 (200 -> 208)
#define XSTR 216       // halfs per X row
#define CSTR 212       // halfs per coeff row
#define HSTR 20        // floats per Hr/gsh row
#define WSTR 208       // halfs per staged-weight row
#define NTAN 8
#define NT4 4          // n-tiles per wave in T phase

#define KSC 1024.0f        // backward-chain scale
#define SSC 64.0f          // tangent-chain scale
#define INV_K (1.0f/1024.0f)
#define INV_KS (1.0f/65536.0f)

typedef _Float16 half8 __attribute__((ext_vector_type(8)));
typedef _Float16 half4v __attribute__((ext_vector_type(4)));
typedef _Float16 half2v __attribute__((ext_vector_type(2)));
typedef float float4v __attribute__((ext_vector_type(4)));

#define S4 (NKC*NMT*64*8)
#define OFF_W1T 0
#define OFF_W2T (S4)
#define OFF_W1  (2*S4)
#define OFF_W2  (3*S4)
#define OFF_W0T (4*S4)
#define OFF_W0  (4*S4 + NMT*64*8)
#define WS_HALFS (4*S4 + NMT*64*8 + NKC*64*8)

// ---------------------------------------------------------------------------
__global__ void prep(const float* __restrict__ W0, const float* __restrict__ W1,
                     const float* __restrict__ W2, _Float16* __restrict__ ws)
{
    int idx = blockIdx.x * 256 + threadIdx.x;
    if (idx >= WS_HALFS) return;
    float v = 0.f;
    if (idx < 4*S4) {
        int arr = idx / S4, e = idx % S4;
        int kc = e / (NMT*64*8); int r = e % (NMT*64*8);
        int mt = r / (64*8); r %= 64*8;
        int lane = r / 8, j = r % 8;
        int m = mt*16 + (lane & 15);
        int k = kc*32 + (lane >> 4)*8 + j;
        if (m < HID && k < HID) {
            if      (arr == 0) v = W1[k*HID + m];
            else if (arr == 1) v = W2[k*HID + m];
            else if (arr == 2) v = W1[m*HID + k];
            else               v = W2[m*HID + k];
        }
    } else if (idx < OFF_W0) {
        int e = idx - OFF_W0T;
        int mt = e / (64*8); int r = e % (64*8);
        int lane = r / 8, j = r % 8;
        int m = mt*16 + (lane & 15);
        int k = (lane >> 4)*8 + j;
        if (m < HID && k < ZD) v = W0[k*HID + m];
    } else {
        int e = idx - OFF_W0;
        int kc = e / (64*8); int r = e % (64*8);
        int lane = r / 8, j = r % 8;
        int m = (lane & 15);
        int k = kc*32 + (lane >> 4)*8 + j;
        if (k < HID) v = W0[m*HID + k];
    }
    ws[idx] = (_Float16)v;
}

// ---------------------------------------------------------------------------
__device__ __forceinline__ half4v pk4(float4v a) {
    half2v lo = __builtin_bit_cast(half2v, __builtin_amdgcn_cvt_pkrtz(a.x, a.y));
    half2v hi = __builtin_bit_cast(half2v, __builtin_amdgcn_cvt_pkrtz(a.z, a.w));
    return __builtin_shufflevector(lo, hi, 0, 1, 2, 3);
}
__device__ __forceinline__ void sig_sp(float x, float& sp, float& sg) {
    float e = __expf(-fabsf(x));
    float r = 1.0f / (1.0f + e);
    sg = (x >= 0.f) ? r : (1.0f - r);
    sp = fmaxf(x, 0.f) + __logf(1.f + e);
}

// Software-pipelined matvec: rolling A-prefetch (global/L2, depth PF) +
// next-kc X prefetch (LDS). Fully unrolled so all indices are static.
template<int NTILES, int MTC>
__device__ __forceinline__ void run_mv(const half8* __restrict__ Asw,
                                       const _Float16* __restrict__ Xsrc,
                                       int mt0, int lane,
                                       float4v acc[2][NTILES])
{
    const int lm = lane & 15, q = lane >> 4;
    constexpr int PF = (NTILES > 1) ? 3 : NKC;   // F phase: prefetch ALL A
#pragma unroll
    for (int m = 0; m < MTC; ++m)
#pragma unroll
        for (int n = 0; n < NTILES; ++n)
            acc[m][n] = (float4v){0.f, 0.f, 0.f, 0.f};

    half8 a[MTC][PF];
#pragma unroll
    for (int p = 0; p < PF; ++p)
#pragma unroll
        for (int m = 0; m < MTC; ++m)
            a[m][p] = Asw[(p*NMT + mt0 + m)*64 + lane];

    half8 x[NTILES];
#pragma unroll
    for (int n = 0; n < NTILES; ++n)
        x[n] = *(const half8*)(Xsrc + (n*16 + lm)*XSTR + q*8);

#pragma unroll
    for (int kc = 0; kc < NKC; ++kc) {
        half8 xn[NTILES];
        if (kc + 1 < NKC)
#pragma unroll
            for (int n = 0; n < NTILES; ++n)
                xn[n] = *(const half8*)(Xsrc + (n*16 + lm)*XSTR + (kc+1)*32 + q*8);
        half8 an[MTC];
        if (kc + PF < NKC)
#pragma unroll
            for (int m = 0; m < MTC; ++m)
                an[m] = Asw[((kc+PF)*NMT + mt0 + m)*64 + lane];

#pragma unroll
        for (int m = 0; m < MTC; ++m)
#pragma unroll
            for (int n = 0; n < NTILES; ++n)
                acc[m][n] = __builtin_amdgcn_mfma_f32_16x16x32_f16(a[m][0], x[n], acc[m][n], 0, 0, 0);

        if (kc + 1 < NKC) {
#pragma unroll
            for (int m = 0; m < MTC; ++m)
#pragma unroll
                for (int p = 0; p + 1 < PF; ++p) a[m][p] = a[m][p+1];
            if (kc + PF < NKC)
#pragma unroll
                for (int m = 0; m < MTC; ++m) a[m][PF-1] = an[m];
#pragma unroll
            for (int n = 0; n < NTILES; ++n) x[n] = xn[n];
        }
    }
}

// ---------------------------------------------------------------------------
__global__ void __launch_bounds__(NTHREADS, 4)
lnn_main(const float* __restrict__ z,
         const float* __restrict__ W0, const float* __restrict__ b0,
         const float* __restrict__ b1, const float* __restrict__ b2,
         const float* __restrict__ W3,
         const _Float16* __restrict__ ws,
         float* __restrict__ out)
{
    __shared__ alignas(16) _Float16 Xt[128*XSTR];
    __shared__ alignas(16) _Float16 Xb[128*XSTR];
    __shared__ alignas(16) _Float16 Cf[5][16*CSTR]; // 0:p0 1:p1 2:c2*K 3:u1'(1-p1) 4:u0'p0(1-p0)
    __shared__ alignas(16) _Float16 Xz[16*40];
    __shared__ alignas(16) _Float16 bsh[4*WSTR];    // b0,b1,b2,KSC*W3 (zero-padded)
    __shared__ alignas(16) _Float16 w0t[NTAN*WSTR]; // SSC*W0[8+t][u] (zero-padded)
    __shared__ alignas(16) float gsh[16*HSTR];
    __shared__ alignas(16) float Hr[128*HSTR];

    const int tid  = threadIdx.x;
    const int wave = tid >> 6;
    const int lane = tid & 63;
    const int lm   = lane & 15;
    const int q    = lane >> 4;
    const int s0   = blockIdx.x * BS;

    // T-phase wave grid: 8 m-groups x 2 n-groups
    const int twm  = wave >> 1;
    const int twn  = wave & 1;
    const int mt0t = (twm < 5) ? twm*2 : (twm + 5);
    const int mtct = (twm < 5) ? 2 : 1;

    const half8* W1Tsw = (const half8*)(ws + OFF_W1T);
    const half8* W2Tsw = (const half8*)(ws + OFF_W2T);
    const half8* W1sw  = (const half8*)(ws + OFF_W1);
    const half8* W2sw  = (const half8*)(ws + OFF_W2);
    const half8* W0Tsw = (const half8*)(ws + OFF_W0T);
    const half8* W0sw  = (const half8*)(ws + OFF_W0);

    // ---- init/staging ----
    if (tid < 256) {
        int s = tid >> 4, k = tid & 15;
        Xz[s*40 + k]      = (_Float16)z[(s0 + s)*ZD + k];
        Xz[s*40 + 16 + k] = (_Float16)0.f;
    }
    for (int idx = tid; idx < 128*16; idx += NTHREADS) {
        int r = idx >> 4, c = 200 + (idx & 15);
        Xt[r*XSTR + c] = (_Float16)0.f;
        Xb[r*XSTR + c] = (_Float16)0.f;
    }
    // CRITICAL: the kc=6,q=3 fragment read of row r spans into row r+1 cols 0..7
    // (XSTR=216 < 224). For F-phase reads of row 15 that is row 16, which is
    // otherwise unwritten until T2 -> uninitialized LDS. A=0 there, but
    // 0*Inf/NaN = NaN in MFMA. Zero it once.
    if (tid < 8) {
        Xt[16*XSTR + tid] = (_Float16)0.f;
        Xb[16*XSTR + tid] = (_Float16)0.f;
    }
    for (int idx = tid; idx < 4*WSTR; idx += NTHREADS) {
        int l = idx / WSTR, u = idx % WSTR;
        float v = 0.f;
        if (u < HID) {
            if      (l == 0) v = b0[u];
            else if (l == 1) v = b1[u];
            else if (l == 2) v = b2[u];
            else             v = KSC * W3[u];
        }
        bsh[idx] = (_Float16)v;
    }
    for (int idx = tid; idx < NTAN*WSTR; idx += NTHREADS) {
        int t = idx / WSTR, u = idx % WSTR;
        w0t[idx] = (_Float16)((u < HID) ? SSC * W0[(DD + t)*HID + u] : 0.f);
    }
    __syncthreads();

    float4v acc1[2][1];
    const int ubf = wave*16 + q*4;   // F-phase unit base (wave<13)

    // ================= F0: a0 = z@W0+b0 =================
    if (wave < NMT) {
        acc1[0][0] = (float4v){0.f,0.f,0.f,0.f};
        half8 xz = *(const half8*)(Xz + lm*40 + q*8);
        half8 a = W0Tsw[wave*64 + lane];
        acc1[0][0] = __builtin_amdgcn_mfma_f32_16x16x32_f16(a, xz, acc1[0][0], 0, 0, 0);
        half4v bb = *(const half4v*)(&bsh[0*WSTR + ubf]);
        float h[4], p[4];
#pragma unroll
        for (int r = 0; r < 4; ++r) {
            float av = acc1[0][0][r] + (float)bb[r];
            sig_sp(av, h[r], p[r]);
        }
        *(half4v*)(&Xt[lm*XSTR + ubf])     = pk4((float4v){h[0],h[1],h[2],h[3]});
        *(half4v*)(&Cf[0][lm*CSTR + ubf])  = pk4((float4v){p[0],p[1],p[2],p[3]});
    }
    __syncthreads();

    // ================= F1 =================
    if (wave < NMT) run_mv<1,1>(W1Tsw, Xt, wave, lane, acc1);
    __syncthreads();   // in-place Xt update: mid-barrier required
    if (wave < NMT) {
        half4v bb = *(const half4v*)(&bsh[1*WSTR + ubf]);
        float h[4], p[4];
#pragma unroll
        for (int r = 0; r < 4; ++r) {
            float av = acc1[0][0][r] + (float)bb[r];
            sig_sp(av, h[r], p[r]);
        }
        *(half4v*)(&Xt[lm*XSTR + ubf])    = pk4((float4v){h[0],h[1],h[2],h[3]});
        *(half4v*)(&Cf[1][lm*CSTR + ubf]) = pk4((float4v){p[0],p[1],p[2],p[3]});
    }
    __syncthreads();

    // ================= F2: d2'=K*w3*sg, c2'=K*w3*sg(1-sg) =================
    if (wave < NMT) run_mv<1,1>(W2Tsw, Xt, wave, lane, acc1);
    __syncthreads();
    if (wave < NMT) {
        half4v bb = *(const half4v*)(&bsh[2*WSTR + ubf]);
        half4v w3 = *(const half4v*)(&bsh[3*WSTR + ubf]);
        float d2[4], c2[4];
#pragma unroll
        for (int r = 0; r < 4; ++r) {
            float av = acc1[0][0][r] + (float)bb[r];
            float e = __expf(-fabsf(av));
            float rr = 1.f / (1.f + e);
            float sg = (av >= 0.f) ? rr : (1.f - rr);
            float wk = (float)w3[r];
            d2[r] = wk * sg;
            c2[r] = wk * sg * (1.f - sg);
        }
        *(half4v*)(&Xt[lm*XSTR + ubf])    = pk4((float4v){d2[0],d2[1],d2[2],d2[3]});
        *(half4v*)(&Cf[2][lm*CSTR + ubf]) = pk4((float4v){c2[0],c2[1],c2[2],c2[3]});
    }
    __syncthreads();

    // ================= B1: u1'=W2 d2'; d1'=u1'p1; Cf3=u1'(1-p1) =================
    if (wave < NMT) run_mv<1,1>(W2sw, Xt, wave, lane, acc1);
    __syncthreads();
    if (wave < NMT) {
        half4v p1 = *(const half4v*)(&Cf[1][lm*CSTR + ubf]);
        half4v u1 = pk4(acc1[0][0]);
        half4v one = {(_Float16)1.f,(_Float16)1.f,(_Float16)1.f,(_Float16)1.f};
        *(half4v*)(&Xt[lm*XSTR + ubf])    = u1 * p1;
        *(half4v*)(&Cf[3][lm*CSTR + ubf]) = u1 * (one - p1);
    }
    __syncthreads();

    // ================= B0: u0'=W1 d1'; d0'=u0'p0; Cf4=u0'p0(1-p0) =================
    if (wave < NMT) run_mv<1,1>(W1sw, Xt, wave, lane, acc1);
    __syncthreads();
    if (wave < NMT) {
        half4v p0 = *(const half4v*)(&Cf[0][lm*CSTR + ubf]);
        half4v u0 = pk4(acc1[0][0]);
        half4v one = {(_Float16)1.f,(_Float16)1.f,(_Float16)1.f,(_Float16)1.f};
        half4v d0 = u0 * p0;
        *(half4v*)(&Xt[lm*XSTR + ubf])    = d0;
        *(half4v*)(&Cf[4][lm*CSTR + ubf]) = d0 * (one - p0);
    }
    __syncthreads();

    // ===== g-projection (wave 0, reads Xt) || th0 build (waves 1-15 -> Xb) =====
    if (wave == 0) {
        half8 aw[NKC];
#pragma unroll
        for (int kc = 0; kc < NKC; ++kc) aw[kc] = W0sw[kc*64 + lane];
        float4v g = (float4v){0.f,0.f,0.f,0.f};
#pragma unroll
        for (int kc = 0; kc < NKC; ++kc) {
            half8 x = *(const half8*)(Xt + lm*XSTR + kc*32 + q*8);
            g = __builtin_amdgcn_mfma_f32_16x16x32_f16(aw[kc], x, g, 0, 0, 0);
        }
        float4v gv; gv.x = g.x*INV_K; gv.y = g.y*INV_K; gv.z = g.z*INV_K; gv.w = g.w*INV_K;
        *(float4v*)(&gsh[lm*HSTR + q*4]) = gv;
    } else {
        for (int idx = tid - 64; idx < 128*50; idx += NTHREADS - 64) {
            int row = idx / 50, u = (idx % 50)*4;
            int s = row & 15, t = row >> 4;
            half4v p0 = *(const half4v*)(&Cf[0][s*CSTR + u]);
            half4v w0 = *(const half4v*)(&w0t[t*WSTR + u]);
            *(half4v*)(&Xb[row*XSTR + u]) = p0 * w0;
        }
    }
    __syncthreads();

    float4v acc4[2][NT4];

    // ========= T2: t1' = th0@W1 (reads Xb) ; th1' = t1'*p1 -> Xt =========
    if (mtct == 2) run_mv<NT4,2>(W1Tsw, Xb + twn*64*XSTR, mt0t, lane, acc4);
    else           run_mv<NT4,1>(W1Tsw, Xb + twn*64*XSTR, mt0t, lane, acc4);
    // no mid-barrier: writes Xt, others read Xb
#pragma unroll
    for (int m = 0; m < 2; ++m)
        if (m < mtct) {
            const int ub = (mt0t + m)*16 + q*4;
            half4v p1 = *(const half4v*)(&Cf[1][lm*CSTR + ub]);
#pragma unroll
            for (int n = 0; n < NT4; ++n) {
                int row = (twn*NT4 + n)*16 + lm;
                *(half4v*)(&Xt[row*XSTR + ub]) = pk4(acc4[m][n]) * p1;
            }
        }
    __syncthreads();

    // ========= T3: t2'' = th1'@W2 (reads Xt) ; d2dot = c2'*t2'' -> Xb =========
    if (mtct == 2) run_mv<NT4,2>(W2Tsw, Xt + twn*64*XSTR, mt0t, lane, acc4);
    else           run_mv<NT4,1>(W2Tsw, Xt + twn*64*XSTR, mt0t, lane, acc4);
    // no mid-barrier: writes Xb, others read Xt
#pragma unroll
    for (int m = 0; m < 2; ++m)
        if (m < mtct) {
            const int ub = (mt0t + m)*16 + q*4;
            half4v c2 = *(const half4v*)(&Cf[2][lm*CSTR + ub]);
#pragma unroll
            for (int n = 0; n < NT4; ++n) {
                int row = (twn*NT4 + n)*16 + lm;
                *(half4v*)(&Xb[row*XSTR + ub]) = pk4(acc4[m][n]) * c2;
            }
        }
    __syncthreads();

    // ========= T4: v1'' = W2 d2dot (reads Xb) ; d1dot = v1''*p1 + c3*th1' -> Xb =========
    if (mtct == 2) run_mv<NT4,2>(W2sw, Xb + twn*64*XSTR, mt0t, lane, acc4);
    else           run_mv<NT4,1>(W2sw, Xb + twn*64*XSTR, mt0t, lane, acc4);
    __syncthreads();   // in-place Xb update: mid-barrier required
#pragma unroll
    for (int m = 0; m < 2; ++m)
        if (m < mtct) {
            const int ub = (mt0t + m)*16 + q*4;
            half4v p1 = *(const half4v*)(&Cf[1][lm*CSTR + ub]);
            half4v c3 = *(const half4v*)(&Cf[3][lm*CSTR + ub]);
#pragma unroll
            for (int n = 0; n < NT4; ++n) {
                int row = (twn*NT4 + n)*16 + lm;
                half4v th1 = *(const half4v*)(&Xt[row*XSTR + ub]);
                *(half4v*)(&Xb[row*XSTR + ub]) = pk4(acc4[m][n]) * p1 + c3 * th1;
            }
        }
    __syncthreads();

    // ========= T5: v0'' = W1 d1dot (reads Xb) ; d0dot = v0''*p0 + c4*(S*t0) -> Xt =========
    if (mtct == 2) run_mv<NT4,2>(W1sw, Xb + twn*64*XSTR, mt0t, lane, acc4);
    else           run_mv<NT4,1>(W1sw, Xb + twn*64*XSTR, mt0t, lane, acc4);
    // no mid-barrier: writes Xt, others read Xb
#pragma unroll
    for (int m = 0; m < 2; ++m)
        if (m < mtct) {
            const int ub = (mt0t + m)*16 + q*4;
            half4v p0 = *(const half4v*)(&Cf[0][lm*CSTR + ub]);
            half4v c4 = *(const half4v*)(&Cf[4][lm*CSTR + ub]);
#pragma unroll
            for (int n = 0; n < NT4; ++n) {
                int row = (twn*NT4 + n)*16 + lm;
                half4v w0 = *(const half4v*)(&w0t[(twn*NT4 + n)*WSTR + ub]);
                *(half4v*)(&Xt[row*XSTR + ub]) = pk4(acc4[m][n]) * p0 + c4 * w0;
            }
        }
    __syncthreads();

    // ========= Hr projection: waves 0-7, nt = wave (reads Xt) =========
    if (wave < 8) {
        half8 aw[NKC];
#pragma unroll
        for (int kc = 0; kc < NKC; ++kc) aw[kc] = W0sw[kc*64 + lane];
        float4v hacc = (float4v){0.f,0.f,0.f,0.f};
#pragma unroll
        for (int kc = 0; kc < NKC; ++kc) {
            half8 x = *(const half8*)(Xt + (wave*16 + lm)*XSTR + kc*32 + q*8);
            hacc = __builtin_amdgcn_mfma_f32_16x16x32_f16(aw[kc], x, hacc, 0, 0, 0);
        }
        int row = wave*16 + lm;
        float4v hv;
        hv.x = hacc.x*INV_KS; hv.y = hacc.y*INV_KS;
        hv.z = hacc.z*INV_KS; hv.w = hacc.w*INV_KS;
        *(float4v*)(&Hr[row*HSTR + q*4]) = hv;
    }
    __syncthreads();

    // ========= per-sample 8x8 solve =========
    if (tid < BS) {
        const int s = tid;
        float M[DD][DD], F[DD], v[DD], a[DD];
#pragma unroll
        for (int c = 0; c < DD; ++c) v[c] = z[(s0 + s)*ZD + DD + c];
#pragma unroll
        for (int r = 0; r < DD; ++r) {
            float f = gsh[s*HSTR + r];
#pragma unroll
            for (int c = 0; c < DD; ++c) {
                M[r][c] = Hr[(r*16 + s)*HSTR + DD + c] + ((r == c) ? 2.f*EPSL : 0.f);
                f -= Hr[(r*16 + s)*HSTR + c] * v[c];
            }
            F[r] = f;
        }
#pragma unroll
        for (int col = 0; col < DD; ++col) {
            const float inv = 1.f / M[col][col];
#pragma unroll
            for (int r = col + 1; r < DD; ++r) {
                const float fac = M[r][col] * inv;
#pragma unroll
                for (int c = col + 1; c < DD; ++c) M[r][c] -= fac * M[col][c];
                F[r] -= fac * F[col];
            }
        }
#pragma unroll
        for (int r = DD - 1; r >= 0; --r) {
            float ssum = F[r];
#pragma unroll
            for (int c = r + 1; c < DD; ++c) ssum -= M[r][c] * a[c];
            a[r] = ssum / M[r][r];
        }
        float* op = out + (size_t)(s0 + s)*ZD;
#pragma unroll
        for (int c = 0; c < DD; ++c) { op[c] = v[c]; op[DD + c] = a[c]; }
    }
}

extern "C" void kernel_launch(void* const* d_in, const int* in_sizes, int n_in,
                              void* d_out, int out_size, void* d_ws, size_t ws_size,
                              hipStream_t stream)
{
    const float* z  = (const float*)d_in[1];
    const float* W0 = (const float*)d_in[2];
    const float* b0 = (const float*)d_in[3];
    const float* W1 = (const float*)d_in[4];
    const float* b1 = (const float*)d_in[5];
    const float* W2 = (const float*)d_in[6];
    const float* b2 = (const float*)d_in[7];
    const float* W3 = (const float*)d_in[8];
    float* out = (float*)d_out;
    _Float16* ws = (_Float16*)d_ws;

    const int n = in_sizes[1] / (2*DD);

    prep<<<dim3((WS_HALFS + 255)/256), dim3(256), 0, stream>>>(W0, W1, W2, ws);
    lnn_main<<<dim3(n / BS), dim3(NTHREADS), 0, stream>>>(
        z, W0, b0, b1, b2, W3, ws, out);
}